// Round 10
// baseline (124.335 us; speedup 1.0000x reference)
//
#include <hip/hip_runtime.h>
#include <hip/hip_bf16.h>
#include <math.h>

#define BB 2
#define NN 16384
#define KK 16
#define CC 128
#define COUT 128
#define NODES (BB * NN)

typedef __attribute__((ext_vector_type(8))) short bf16x8;
typedef __attribute__((ext_vector_type(4))) float f32x4;
typedef __attribute__((ext_vector_type(2))) float f32x2;  // matches fp8 builtin returns

__device__ __forceinline__ bf16x8 cvt8(f32x4 a, f32x4 b) {
    union { bf16x8 v; __hip_bfloat162 h[4]; } u;
    u.h[0] = __float22bfloat162_rn(make_float2(a[0], a[1]));
    u.h[1] = __float22bfloat162_rn(make_float2(a[2], a[3]));
    u.h[2] = __float22bfloat162_rn(make_float2(b[0], b[1]));
    u.h[3] = __float22bfloat162_rn(make_float2(b[2], b[3]));
    return u.v;
}

// DPP row_ror adds within each 16-lane row (VALU pipe).
template <int CTRL>
__device__ __forceinline__ float rot_add(float v) {
    int r = __builtin_amdgcn_update_dpp(0, __float_as_int(v), CTRL, 0xF, 0xF, true);
    return v + __int_as_float(r);
}
__device__ __forceinline__ float row16_sum(float v) {
    v = rot_add<0x128>(v); v = rot_add<0x124>(v);
    v = rot_add<0x122>(v); v = rot_add<0x121>(v);
    return v;
}
__device__ __forceinline__ float row16_sum4(float v) {
    v = rot_add<0x128>(v); v = rot_add<0x124>(v);
    return v;
}

// ---------------------------------------------------------------------------
// Kernel P: x (fp32) -> xh (bf16) + xq (fp8 e4m3), streaming. 8 elems/thread.
// ---------------------------------------------------------------------------
__global__ __launch_bounds__(256) void cast_x(
    const float* __restrict__ x,
    __hip_bfloat16* __restrict__ xh,
    unsigned char* __restrict__ xq)
{
    const int i = blockIdx.x * 256 + threadIdx.x;
    const f32x4* p = (const f32x4*)(x + (size_t)i * 8);
    f32x4 a = __builtin_nontemporal_load(p);
    f32x4 b = __builtin_nontemporal_load(p + 1);
    *(bf16x8*)(xh + (size_t)i * 8) = cvt8(a, b);
    int lo = __builtin_amdgcn_cvt_pk_fp8_f32(a[0], a[1], 0, false);
    lo     = __builtin_amdgcn_cvt_pk_fp8_f32(a[2], a[3], lo, true);
    int hi = __builtin_amdgcn_cvt_pk_fp8_f32(b[0], b[1], 0, false);
    hi     = __builtin_amdgcn_cvt_pk_fp8_f32(b[2], b[3], hi, true);
    int2 v; v.x = lo; v.y = hi;
    *(int2*)(xq + (size_t)i * 8) = v;
}

// Softmax column-sum: scores (C-layout) -> w for this lane's Xj row m.
__device__ __forceinline__ float col_weight(f32x4 acc) {
    const float scale = 0.08838834764831843f;  // 1/sqrt(128)
    float w = 0.f;
    #pragma unroll
    for (int i = 0; i < 4; ++i) {
        float e = __expf(acc[i] * scale);
        float s = row16_sum(e);
        w += e * __builtin_amdgcn_rcpf(s);
    }
    w += __shfl_xor(w, 16, 64);
    w += __shfl_xor(w, 32, 64);
    return w;
}

// h-reduction: lane's Xj row (bf16 frags) scaled by wj, DPP 16->4 rows +
// per-wave LDS bounce 4->1. Returns lane's channels (2L, 2L+1).
__device__ __forceinline__ float2 reduce_h(const bf16x8* bfr, float wj,
                                           float* hb, int m, int q, int lane) {
    #pragma unroll
    for (int s = 0; s < 4; ++s) {
        union { bf16x8 v; unsigned short u[8]; } ub;
        ub.v = bfr[s];
        float f[8];
        #pragma unroll
        for (int e = 0; e < 8; ++e) {
            f[e] = __uint_as_float((unsigned)ub.u[e] << 16) * wj;
            f[e] = row16_sum4(f[e]);
        }
        if (m < 4) {
            f32x4 lo = {f[0], f[1], f[2], f[3]};
            f32x4 hi = {f[4], f[5], f[6], f[7]};
            *(f32x4*)&hb[m * 132 + 32 * s + 8 * q]     = lo;
            *(f32x4*)&hb[m * 132 + 32 * s + 8 * q + 4] = hi;
        }
    }
    float hx = 0.f, hy = 0.f;
    #pragma unroll
    for (int r = 0; r < 4; ++r) {
        float2 v = *(const float2*)&hb[r * 132 + 2 * lane];
        hx += v.x; hy += v.y;
    }
    return make_float2(hx, hy);
}

// ---------------------------------------------------------------------------
// Kernel A: one node per wave, DIRECT divergent gathers straight into MFMA
// fragment (m,q) layout — no staging LDS (coalescing proved neutral in R7;
// the lines dominate, not the lane divergence). LDS = hbuf only (8.4 KB)
// -> 6-8 blocks/CU resident for max outstanding-miss concurrency.
// Xi from fp8 (2 lines/row), Xj from bf16 (4 lines/row).
// ---------------------------------------------------------------------------
__global__ __launch_bounds__(256, 6) void attn_phase(
    const __hip_bfloat16* __restrict__ xh,
    const unsigned char* __restrict__ xq,
    const int* __restrict__ edge,
    __hip_bfloat16* __restrict__ z)
{
    __shared__ float hbuf[4][4 * 132];  // 8.4 KB/block

    const int t = threadIdx.x;
    const int wv = t >> 6;
    const int lane = t & 63;
    const int m = lane & 15;   // fragment row
    const int q = lane >> 4;   // fragment k-quad
    const int node = blockIdx.x * 4 + wv;
    const int b = node >> 14;
    const __hip_bfloat16* xbh = xh + (size_t)b * (size_t)(NN * CC);
    const unsigned char*  xbq = xq + (size_t)b * (size_t)(NN * CC);

    // Per-lane edge indices (row m; 4-way redundant across quads)
    const size_t ebase = (size_t)node * KK + m;
    const int idx_j = edge[ebase];                         // edge[0]: neighbors
    const int idx_i = edge[(size_t)(NODES * KK) + ebase];  // edge[1]: centers

    // All gathers issued before any dependent math (10 loads in flight/wave)
    const unsigned char*  pi = xbq + (size_t)idx_i * CC + q * 8;  // fp8: 1 B/ch
    const __hip_bfloat16* pj = xbh + (size_t)idx_j * CC + q * 8;
    int2 qi[4];
    bf16x8 bfr[4];
    #pragma unroll
    for (int s = 0; s < 4; ++s) {
        qi[s]  = *(const int2*)(pi + 32 * s);
        bfr[s] = *(const bf16x8*)(pj + 32 * s);
    }
    // Residual row (sequential, coalesced)
    const int n0 = node & (NN - 1);
    __hip_bfloat162 rx = *(const __hip_bfloat162*)(xbh + (size_t)n0 * CC + 2 * lane);

    // Upconvert Xi fp8 -> bf16 (exact: e4m3 subset of bf16)
    bf16x8 afr[4];
    #pragma unroll
    for (int s = 0; s < 4; ++s) {
        f32x2 f0 = __builtin_amdgcn_cvt_pk_f32_fp8(qi[s].x, false);
        f32x2 f1 = __builtin_amdgcn_cvt_pk_f32_fp8(qi[s].x, true);
        f32x2 f2 = __builtin_amdgcn_cvt_pk_f32_fp8(qi[s].y, false);
        f32x2 f3 = __builtin_amdgcn_cvt_pk_f32_fp8(qi[s].y, true);
        union { bf16x8 v; __hip_bfloat162 h[4]; } u;
        u.h[0] = __float22bfloat162_rn(make_float2(f0[0], f0[1]));
        u.h[1] = __float22bfloat162_rn(make_float2(f1[0], f1[1]));
        u.h[2] = __float22bfloat162_rn(make_float2(f2[0], f2[1]));
        u.h[3] = __float22bfloat162_rn(make_float2(f3[0], f3[1]));
        afr[s] = u.v;
    }

    // Scores S[k][j] = Xi[k]·Xj[j] (16x16, K=128)
    f32x4 acc = {0.f, 0.f, 0.f, 0.f};
    #pragma unroll
    for (int s = 0; s < 4; ++s)
        acc = __builtin_amdgcn_mfma_f32_16x16x32_bf16(afr[s], bfr[s], acc, 0, 0, 0);

    // Softmax col-sum (no max-sub: scaled scores ~N(0,1), exp-safe)
    const float wj = col_weight(acc);

    // h = sum_j w[j] * Xj[j][:]
    float2 h = reduce_h(bfr, wj, &hbuf[wv][0], m, q, lane);

    // Residual + cast + store (coalesced 256 B/node)
    float2 xc = __bfloat1622float2(rx);
    *(__hip_bfloat162*)(z + (size_t)node * CC + 2 * lane) =
        __float22bfloat162_rn(make_float2(xc.x + h.x, xc.y + h.y));
}

// ---------------------------------------------------------------------------
// Kernel B: Y = relu(Z_bf16 @ W^T + b) via bf16 MFMA. One wave owns one
// 16-col N-tile (B frag loaded once) and iterates 4 M-tiles. No LDS.
// ---------------------------------------------------------------------------
__global__ __launch_bounds__(256, 4) void linear_relu(
    const __hip_bfloat16* __restrict__ z,
    const float* __restrict__ W,
    const float* __restrict__ bias,
    float* __restrict__ out)
{
    const int t = threadIdx.x;
    const int lane = t & 63;
    const int wid = blockIdx.x * 4 + (t >> 6);  // 0..4095
    const int ntile = wid & 7;                  // 8 N-tiles of 16 cols
    const int m0 = wid >> 3;                    // 0..511 starting M-tile
    const int nm = lane & 15;
    const int nq = lane >> 4;

    const float* wp = W + (size_t)(ntile * 16 + nm) * CC + nq * 8;
    bf16x8 bfr[4];
    #pragma unroll
    for (int s = 0; s < 4; ++s) {
        f32x4 w0 = *(const f32x4*)(wp + 32 * s);
        f32x4 w1 = *(const f32x4*)(wp + 32 * s + 4);
        bfr[s] = cvt8(w0, w1);
    }
    const float bv = bias[ntile * 16 + nm];

    #pragma unroll
    for (int it = 0; it < 4; ++it) {
        const int mt = m0 + it * 512;
        const __hip_bfloat16* zp = z + (size_t)(mt * 16 + nm) * CC + nq * 8;
        bf16x8 afr[4];
        #pragma unroll
        for (int s = 0; s < 4; ++s)
            afr[s] = *(const bf16x8*)(zp + 32 * s);
        f32x4 acc = {0.f, 0.f, 0.f, 0.f};
        #pragma unroll
        for (int s = 0; s < 4; ++s)
            acc = __builtin_amdgcn_mfma_f32_16x16x32_bf16(afr[s], bfr[s], acc, 0, 0, 0);
        float* op = out + (size_t)(mt * 16 + nq * 4) * COUT + ntile * 16 + nm;
        #pragma unroll
        for (int i = 0; i < 4; ++i)
            op[(size_t)i * COUT] = fmaxf(acc[i] + bv, 0.f);
    }
}

extern "C" void kernel_launch(void* const* d_in, const int* in_sizes, int n_in,
                              void* d_out, int out_size, void* d_ws, size_t ws_size,
                              hipStream_t stream) {
    const float* x    = (const float*)d_in[0];
    const int*   edge = (const int*)d_in[1];
    const float* W    = (const float*)d_in[2];
    const float* bias = (const float*)d_in[3];
    float* out = (float*)d_out;
    __hip_bfloat16* z  = (__hip_bfloat16*)d_ws;                       // 8 MB
    __hip_bfloat16* xh = (__hip_bfloat16*)d_ws + (size_t)NODES * CC;  // 8 MB
    unsigned char*  xq = (unsigned char*)d_ws + 16 * 1024 * 1024;     // 4 MB

    cast_x<<<(NODES * CC) / (256 * 8), 256, 0, stream>>>(x, xh, xq);
    attn_phase<<<NODES / 4, 256, 0, stream>>>(xh, xq, edge, z);
    linear_relu<<<1024, 256, 0, stream>>>(z, W, bias, out);
}

// Round 11
// 112.137 us; speedup vs baseline: 1.1088x; 1.1088x over previous
//
#include <hip/hip_runtime.h>
#include <hip/hip_bf16.h>
#include <math.h>

#define BB 2
#define NN 16384
#define KK 16
#define CC 128
#define COUT 128
#define NODES (BB * NN)
#define SP 136   // bf16 staging row pitch (elements; 272 B)
#define SQP 136  // fp8 staging row pitch (bytes)

typedef __attribute__((ext_vector_type(8))) short bf16x8;
typedef __attribute__((ext_vector_type(4))) float f32x4;
typedef __attribute__((ext_vector_type(2))) float f32x2;  // matches fp8 builtin returns

__device__ __forceinline__ bf16x8 cvt8(f32x4 a, f32x4 b) {
    union { bf16x8 v; __hip_bfloat162 h[4]; } u;
    u.h[0] = __float22bfloat162_rn(make_float2(a[0], a[1]));
    u.h[1] = __float22bfloat162_rn(make_float2(a[2], a[3]));
    u.h[2] = __float22bfloat162_rn(make_float2(b[0], b[1]));
    u.h[3] = __float22bfloat162_rn(make_float2(b[2], b[3]));
    return u.v;
}

// DPP row_ror adds within each 16-lane row (VALU pipe).
template <int CTRL>
__device__ __forceinline__ float rot_add(float v) {
    int r = __builtin_amdgcn_update_dpp(0, __float_as_int(v), CTRL, 0xF, 0xF, true);
    return v + __int_as_float(r);
}
__device__ __forceinline__ float row16_sum(float v) {
    v = rot_add<0x128>(v); v = rot_add<0x124>(v);
    v = rot_add<0x122>(v); v = rot_add<0x121>(v);
    return v;
}
__device__ __forceinline__ float row16_sum4(float v) {
    v = rot_add<0x128>(v); v = rot_add<0x124>(v);
    return v;
}

// ---------------------------------------------------------------------------
// Kernel P: x (fp32) -> xh (bf16) + xq (fp8 e4m3), streaming. 8 elems/thread.
// ---------------------------------------------------------------------------
__global__ __launch_bounds__(256) void cast_x(
    const float* __restrict__ x,
    __hip_bfloat16* __restrict__ xh,
    unsigned char* __restrict__ xq)
{
    const int i = blockIdx.x * 256 + threadIdx.x;
    const f32x4* p = (const f32x4*)(x + (size_t)i * 8);
    f32x4 a = __builtin_nontemporal_load(p);
    f32x4 b = __builtin_nontemporal_load(p + 1);
    *(bf16x8*)(xh + (size_t)i * 8) = cvt8(a, b);
    int lo = __builtin_amdgcn_cvt_pk_fp8_f32(a[0], a[1], 0, false);
    lo     = __builtin_amdgcn_cvt_pk_fp8_f32(a[2], a[3], lo, true);
    int hi = __builtin_amdgcn_cvt_pk_fp8_f32(b[0], b[1], 0, false);
    hi     = __builtin_amdgcn_cvt_pk_fp8_f32(b[2], b[3], hi, true);
    int2 v; v.x = lo; v.y = hi;
    *(int2*)(xq + (size_t)i * 8) = v;
}

// Softmax column-sum: scores (C-layout) -> w for this lane's Xj row m.
__device__ __forceinline__ float col_weight(f32x4 acc) {
    const float scale = 0.08838834764831843f;  // 1/sqrt(128)
    float w = 0.f;
    #pragma unroll
    for (int i = 0; i < 4; ++i) {
        float e = __expf(acc[i] * scale);
        float s = row16_sum(e);
        w += e * __builtin_amdgcn_rcpf(s);
    }
    w += __shfl_xor(w, 16, 64);
    w += __shfl_xor(w, 32, 64);
    return w;
}

// h-reduction: lane's Xj row (bf16 frags) scaled by wj, DPP 16->4 rows +
// per-wave LDS bounce 4->1. Returns lane's channels (2L, 2L+1).
__device__ __forceinline__ float2 reduce_h(const bf16x8* bfr, float wj,
                                           float* hb, int m, int q, int lane) {
    #pragma unroll
    for (int s = 0; s < 4; ++s) {
        union { bf16x8 v; unsigned short u[8]; } ub;
        ub.v = bfr[s];
        float f[8];
        #pragma unroll
        for (int e = 0; e < 8; ++e) {
            f[e] = __uint_as_float((unsigned)ub.u[e] << 16) * wj;
            f[e] = row16_sum4(f[e]);
        }
        if (m < 4) {
            f32x4 lo = {f[0], f[1], f[2], f[3]};
            f32x4 hi = {f[4], f[5], f[6], f[7]};
            *(f32x4*)&hb[m * 132 + 32 * s + 8 * q]     = lo;
            *(f32x4*)&hb[m * 132 + 32 * s + 8 * q + 4] = hi;
        }
    }
    float hx = 0.f, hy = 0.f;
    #pragma unroll
    for (int r = 0; r < 4; ++r) {
        float2 v = *(const float2*)&hb[r * 132 + 2 * lane];
        hx += v.x; hy += v.y;
    }
    return make_float2(hx, hy);
}

// ---------------------------------------------------------------------------
// Kernel A (R9 structure + LDS aliasing): one node per wave, coalesced staged
// gathers (Xi fp8 2 lines/row, Xj bf16 4 lines/row). hbuf ALIASES the fp8
// staging buffer — stgq is fully consumed (ds_read -> afr -> MFMA -> wj)
// before reduce_h's first hbuf ds_write, and the write's data depends on wj,
// so in-order per-wave DS execution guarantees safety. LDS/block 34.5->25.5KB
// -> up to 6 blocks/CU resident (was 4).
// ---------------------------------------------------------------------------
__global__ __launch_bounds__(256) void attn_phase(
    const __hip_bfloat16* __restrict__ xh,
    const unsigned char* __restrict__ xq,
    const int* __restrict__ edge,
    __hip_bfloat16* __restrict__ z)
{
    __shared__ __hip_bfloat16 stgj[4][16 * SP];             // Xj bf16: 17.4 KB
    __shared__ alignas(16) unsigned char stgq[4][16 * SQP]; // Xi fp8 / hbuf: 8.7 KB

    const int t = threadIdx.x;
    const int wv = t >> 6;
    const int lane = t & 63;
    const int m = lane & 15;   // fragment row
    const int q = lane >> 4;   // fragment k-quad
    const int r = lane >> 4;   // staging: row-in-group 0..3
    const int c = lane & 15;   // staging: chunk 0..15 within row

    const int node = blockIdx.x * 4 + wv;
    const int b = node >> 14;
    const __hip_bfloat16* xbh = xh + (size_t)b * (size_t)(NN * CC);
    const unsigned char*  xbq = xq + (size_t)b * (size_t)(NN * CC);
    __hip_bfloat16* sj = &stgj[wv][0];
    unsigned char*  sq = &stgq[wv][0];

    const int* ej = edge + (size_t)node * KK;   // edge[0]: neighbors j
    const int* ei = ej + (size_t)NODES * KK;    // edge[1]: centers i

    // ---- coalesced gathers ----
    // Xi (fp8): 4 inst, each 4 rows x 128 B (dwordx2/lane)
    int2 ldq[4];
    #pragma unroll
    for (int g = 0; g < 4; ++g) {
        int ridx = __builtin_nontemporal_load(ei + g * 4 + r);
        ldq[g] = *(const int2*)(xbq + (size_t)ridx * CC + c * 8);
    }
    // Xj (bf16): 4 inst, each 4 rows x 256 B (dwordx4/lane)
    bf16x8 ldj[4];
    #pragma unroll
    for (int g = 0; g < 4; ++g) {
        int ridx = __builtin_nontemporal_load(ej + g * 4 + r);
        ldj[g] = *(const bf16x8*)(xbh + (size_t)ridx * CC + c * 8);
    }
    // Residual row (sequential; issue before LDS phase)
    const int n0 = node & (NN - 1);
    __hip_bfloat162 rx = *(const __hip_bfloat162*)(xbh + (size_t)n0 * CC + 2 * lane);

    // ---- stage to LDS ----
    #pragma unroll
    for (int g = 0; g < 4; ++g)
        *(int2*)(sq + (g * 4 + r) * SQP + c * 8) = ldq[g];
    #pragma unroll
    for (int g = 0; g < 4; ++g)
        *(bf16x8*)(sj + (g * 4 + r) * SP + c * 8) = ldj[g];

    // ---- read fragments back in (m,q) layout; upconvert Xi fp8->bf16 ----
    bf16x8 afr[4], bfr[4];
    #pragma unroll
    for (int s = 0; s < 4; ++s) {
        int2 wb = *(const int2*)(sq + m * SQP + s * 32 + q * 8);
        f32x2 f0 = __builtin_amdgcn_cvt_pk_f32_fp8(wb.x, false);
        f32x2 f1 = __builtin_amdgcn_cvt_pk_f32_fp8(wb.x, true);
        f32x2 f2 = __builtin_amdgcn_cvt_pk_f32_fp8(wb.y, false);
        f32x2 f3 = __builtin_amdgcn_cvt_pk_f32_fp8(wb.y, true);
        union { bf16x8 v; __hip_bfloat162 h[4]; } u;
        u.h[0] = __float22bfloat162_rn(make_float2(f0[0], f0[1]));
        u.h[1] = __float22bfloat162_rn(make_float2(f1[0], f1[1]));
        u.h[2] = __float22bfloat162_rn(make_float2(f2[0], f2[1]));
        u.h[3] = __float22bfloat162_rn(make_float2(f3[0], f3[1]));
        afr[s] = u.v;
        bfr[s] = *(const bf16x8*)(sj + m * SP + s * 32 + q * 8);
    }

    // ---- scores S[k][j] = Xi[k]·Xj[j] (16x16, K=128) ----
    f32x4 acc = {0.f, 0.f, 0.f, 0.f};
    #pragma unroll
    for (int s = 0; s < 4; ++s)
        acc = __builtin_amdgcn_mfma_f32_16x16x32_bf16(afr[s], bfr[s], acc, 0, 0, 0);

    // ---- softmax col-sum (no max-sub: scaled scores small, exp-safe) ----
    const float wj = col_weight(acc);

    // ---- h = sum_j w[j] * Xj[j][:] (hbuf aliases sq — consumed above) ----
    float2 h = reduce_h(bfr, wj, (float*)sq, m, q, lane);

    // ---- residual + cast + store ----
    float2 xc = __bfloat1622float2(rx);
    *(__hip_bfloat162*)(z + (size_t)node * CC + 2 * lane) =
        __float22bfloat162_rn(make_float2(xc.x + h.x, xc.y + h.y));
}

// ---------------------------------------------------------------------------
// Kernel B: Y = relu(Z_bf16 @ W^T + b) via bf16 MFMA. One wave owns one
// 16-col N-tile (B frag loaded once) and iterates 4 M-tiles. No LDS.
// ---------------------------------------------------------------------------
__global__ __launch_bounds__(256, 4) void linear_relu(
    const __hip_bfloat16* __restrict__ z,
    const float* __restrict__ W,
    const float* __restrict__ bias,
    float* __restrict__ out)
{
    const int t = threadIdx.x;
    const int lane = t & 63;
    const int wid = blockIdx.x * 4 + (t >> 6);  // 0..4095
    const int ntile = wid & 7;                  // 8 N-tiles of 16 cols
    const int m0 = wid >> 3;                    // 0..511 starting M-tile
    const int nm = lane & 15;
    const int nq = lane >> 4;

    const float* wp = W + (size_t)(ntile * 16 + nm) * CC + nq * 8;
    bf16x8 bfr[4];
    #pragma unroll
    for (int s = 0; s < 4; ++s) {
        f32x4 w0 = *(const f32x4*)(wp + 32 * s);
        f32x4 w1 = *(const f32x4*)(wp + 32 * s + 4);
        bfr[s] = cvt8(w0, w1);
    }
    const float bv = bias[ntile * 16 + nm];

    #pragma unroll
    for (int it = 0; it < 4; ++it) {
        const int mt = m0 + it * 512;
        const __hip_bfloat16* zp = z + (size_t)(mt * 16 + nm) * CC + nq * 8;
        bf16x8 afr[4];
        #pragma unroll
        for (int s = 0; s < 4; ++s)
            afr[s] = *(const bf16x8*)(zp + 32 * s);
        f32x4 acc = {0.f, 0.f, 0.f, 0.f};
        #pragma unroll
        for (int s = 0; s < 4; ++s)
            acc = __builtin_amdgcn_mfma_f32_16x16x32_bf16(afr[s], bfr[s], acc, 0, 0, 0);
        float* op = out + (size_t)(mt * 16 + nq * 4) * COUT + ntile * 16 + nm;
        #pragma unroll
        for (int i = 0; i < 4; ++i)
            op[(size_t)i * COUT] = fmaxf(acc[i] + bv, 0.f);
    }
}

extern "C" void kernel_launch(void* const* d_in, const int* in_sizes, int n_in,
                              void* d_out, int out_size, void* d_ws, size_t ws_size,
                              hipStream_t stream) {
    const float* x    = (const float*)d_in[0];
    const int*   edge = (const int*)d_in[1];
    const float* W    = (const float*)d_in[2];
    const float* bias = (const float*)d_in[3];
    float* out = (float*)d_out;
    __hip_bfloat16* z  = (__hip_bfloat16*)d_ws;                       // 8 MB
    __hip_bfloat16* xh = (__hip_bfloat16*)d_ws + (size_t)NODES * CC;  // 8 MB
    unsigned char*  xq = (unsigned char*)d_ws + 16 * 1024 * 1024;     // 4 MB

    cast_x<<<(NODES * CC) / (256 * 8), 256, 0, stream>>>(x, xh, xq);
    attn_phase<<<NODES / 4, 256, 0, stream>>>(xh, xq, edge, z);
    linear_relu<<<1024, 256, 0, stream>>>(z, W, bias, out);
}